// Round 13
// baseline (284.073 us; speedup 1.0000x reference)
//
#include <hip/hip_runtime.h>
#include <stdint.h>

// Problem constants: B=4, N=32768, K=16, nqueries=2048, stride=16.
#define NPTS  32768
#define NQ    2048
#define KNN   16
#define NB    4
#define NBUCK 512
#define Z0    (-5.2f)
#define ZSCALE (NBUCK / 10.4f)     // buckets over z in [-5.2, 5.2]; ends are clamped
#define INVS  (10.4f / NBUCK)
#define EPSZ  1e-3f                // conservative edge margin >> fp bucket rounding

// ---- d_ws layout (needs 1,851,392 B; R12 proved ws >= 2 MB) ----
// s_xyz : float [NB*NPTS*3]        @ 0         (1,572,864 B) coords in z-bucket order
// s_idx : ushort[NB*NPTS]          @ 1,572,864 (  262,144 B) original index per slot
// cnt   : int   [NB*NBUCK]         @ 1,835,008 (    8,192 B) histogram
// bend  : int   [NB*NBUCK]         @ 1,843,200 (    8,192 B) excl-prefix -> bucket ends

__device__ __forceinline__ int zbucket(float z) {
    int bk = (int)((z - Z0) * ZSCALE);
    return min(max(bk, 0), NBUCK - 1);
}

__device__ __forceinline__ int dpp_shr1_i(int x) {
    return __builtin_amdgcn_update_dpp(x, x, 0x111, 0xf, 0xf, false);
}
__device__ __forceinline__ float dpp_shr1_f(float x) {
    return __int_as_float(dpp_shr1_i(__float_as_int(x)));
}
__device__ __forceinline__ float readlane_f(float x, int l) {
    return __int_as_float(__builtin_amdgcn_readlane(__float_as_int(x), l));
}

// Exact distributed top-16 (Q=1/wave): sorted list (ascending by (dist,idx))
// in lanes 0..15; lane 15 holds exact threshold tau. Candidates gated by
// act && d <= tau; ties resolved exactly inside (pos==16 -> no-op).
__device__ __forceinline__ void insert1(float d, int p, bool act, int lane,
                                        float& ld, int& li, float& tau)
{
    unsigned long long rem = __ballot(act && (d <= tau));
    while (rem) {
        const int srcl = __ffsll(rem) - 1;           // wave-uniform
        const float wd = readlane_f(d, srcl);
        const int   wi = __builtin_amdgcn_readlane(p, srcl);
        const bool less = (ld < wd) || (ld == wd && li < wi);
        const unsigned long long lm = __ballot(less);
        const int pos = __popc((unsigned)(lm & 0xffffull));
        const float pld = dpp_shr1_f(ld);
        const int   pli = dpp_shr1_i(li);
        if (lane < KNN) {
            if (lane == pos)      { ld = wd;  li = wi; }
            else if (lane > pos)  { ld = pld; li = pli; }
        }
        tau = readlane_f(ld, 15);
        rem &= rem - 1;
        if (rem) rem &= __ballot(d <= tau);          // re-gate survivors
    }
}

// ---- prep pipeline ----
__global__ __launch_bounds__(256) void zero_k(int* cnt) {
    cnt[blockIdx.x * 256 + threadIdx.x] = 0;         // grid 8 -> 2048 ints
}

__global__ __launch_bounds__(256) void hist_k(const float* __restrict__ xyz,
                                              int* __restrict__ cnt) {
    const int i = blockIdx.x * 256 + threadIdx.x;    // [0, NB*NPTS)
    const int b = i >> 15;
    const float z = xyz[(size_t)i * 3 + 2];
    atomicAdd(&cnt[b * NBUCK + zbucket(z)], 1);
}

__global__ __launch_bounds__(NBUCK) void prefix_k(const int* __restrict__ cnt,
                                                  int* __restrict__ bend) {
    __shared__ int s[NBUCK];
    const int t = threadIdx.x, b = blockIdx.x;
    const int my = cnt[b * NBUCK + t];
    s[t] = my;
    __syncthreads();
    for (int off = 1; off < NBUCK; off <<= 1) {      // Hillis-Steele inclusive
        const int v = (t >= off) ? s[t - off] : 0;
        __syncthreads();
        s[t] += v;
        __syncthreads();
    }
    bend[b * NBUCK + t] = s[t] - my;                 // exclusive prefix (scatter cursor)
}

__global__ __launch_bounds__(256) void scatter_k(const float* __restrict__ xyz,
                                                 int* __restrict__ bend,
                                                 float* __restrict__ s_xyz,
                                                 unsigned short* __restrict__ s_idx) {
    const int i = blockIdx.x * 256 + threadIdx.x;    // [0, NB*NPTS)
    const int b = i >> 15;
    const int pi = i & (NPTS - 1);
    const float x = xyz[(size_t)i * 3 + 0];
    const float y = xyz[(size_t)i * 3 + 1];
    const float z = xyz[(size_t)i * 3 + 2];
    const int pos = atomicAdd(&bend[b * NBUCK + zbucket(z)], 1);
    const size_t o = (size_t)b * NPTS + pos;
    s_xyz[3 * o + 0] = x;
    s_xyz[3 * o + 1] = y;
    s_xyz[3 * o + 2] = z;
    s_idx[o] = (unsigned short)pi;
}   // afterwards bend[b][k] == end index of bucket k (within batch)

// ---- query kernel: one wave per query, exact pruned outward bucket walk ----
__global__ __launch_bounds__(256) void knn_kernel(const float* __restrict__ xyz,
                                                  const float* __restrict__ s_xyz,
                                                  const unsigned short* __restrict__ s_idx,
                                                  const int* __restrict__ bend,
                                                  float* __restrict__ out_idx,
                                                  float* __restrict__ out_pts)
{
    const int tid  = threadIdx.x;
    const int lane = tid & 63;
    const int wv   = tid >> 6;
    const int w    = blockIdx.x * 4 + wv;            // wave = query, [0, 8192)
    const int b    = w >> 11;
    const int qi   = w & (NQ - 1);
    const size_t xb = (size_t)b * NPTS * 3;

    const float qx = xyz[xb + 48 * qi + 0];          // 3 * (16*qi)
    const float qy = xyz[xb + 48 * qi + 1];
    const float qz = xyz[xb + 48 * qi + 2];

    const int g = b * NQ + qi;
    if (lane == 0) {
        out_pts[3 * g + 0] = qx;
        out_pts[3 * g + 1] = qy;
        out_pts[3 * g + 2] = qz;
    }

    float ld = __builtin_inff();  int li = 0x7fffffff;
    float tau = __builtin_inff();

    const int qb = zbucket(qz);                      // any qb is correct; this is optimal
    const int cb = b * NBUCK;
    const float* sx = s_xyz + xb;
    const unsigned short* si = s_idx + (size_t)b * NPTS;

    int nextR = qb, nextL = qb - 1;
    for (;;) {
        // Direction viability + conservative z-only lower bounds.
        float dR = __builtin_inff(), dL = __builtin_inff();
        if (nextR < NBUCK) {
            const float gap = (nextR == qb) ? 0.f
                : fmaxf(__fmaf_rn((float)nextR, INVS, Z0 - EPSZ) - qz, 0.f);
            dR = gap * gap;
            if (dR > tau) { nextR = NBUCK; dR = __builtin_inff(); }  // permanent: tau only shrinks
        }
        if (nextL >= 0) {
            const float gap = fmaxf(qz - __fmaf_rn((float)(nextL + 1), INVS, Z0 + EPSZ), 0.f);
            dL = gap * gap;
            if (dL > tau) { nextL = -1; dL = __builtin_inff(); }
        }
        int sb;
        if (nextR < NBUCK && dR <= dL) sb = nextR++;
        else if (nextL >= 0)           sb = nextL--;
        else break;

        const int lo = (sb == 0) ? 0 : bend[cb + sb - 1];
        const int hi = bend[cb + sb];
        for (int i = lo; i < hi; i += 64) {
            const int id  = i + lane;
            const bool ok = id < hi;
            const int cid = ok ? id : (hi - 1);
            const float px = sx[3 * cid + 0];
            const float py = sx[3 * cid + 1];
            const float pz = sx[3 * cid + 2];
            const int  pidx = (int)si[cid];
            // exact numpy distance: ((dx*dx + dy*dy) + dz*dz), each op rn
            const float dx = __fadd_rn(px, -qx);
            const float dy = __fadd_rn(py, -qy);
            const float dz = __fadd_rn(pz, -qz);
            const float d  = __fadd_rn(
                __fadd_rn(__fmul_rn(dx, dx), __fmul_rn(dy, dy)),
                __fmul_rn(dz, dz));
            insert1(d, pidx, ok, lane, ld, li, tau);
        }
    }

    if (lane < KNN)
        out_idx[(size_t)g * KNN + lane] = (float)li;
}

extern "C" void kernel_launch(void* const* d_in, const int* in_sizes, int n_in,
                              void* d_out, int out_size, void* d_ws, size_t ws_size,
                              hipStream_t stream) {
    const float* xyz = (const float*)d_in[0];
    float* out = (float*)d_out;
    float* out_idx = out;                                 // NB*NQ*KNN floats
    float* out_pts = out + (size_t)NB * NQ * KNN;         // NB*NQ*3 floats

    char* ws = (char*)d_ws;
    float* s_xyz         = (float*)ws;                    // 1,572,864 B
    unsigned short* s_idx = (unsigned short*)(ws + 1572864); //   262,144 B
    int* cnt             = (int*)(ws + 1835008);          //     8,192 B
    int* bend            = (int*)(ws + 1843200);          //     8,192 B

    zero_k   <<<8,    256,   0, stream>>>(cnt);
    hist_k   <<<512,  256,   0, stream>>>(xyz, cnt);
    prefix_k <<<NB,   NBUCK, 0, stream>>>(cnt, bend);
    scatter_k<<<512,  256,   0, stream>>>(xyz, bend, s_xyz, s_idx);
    knn_kernel<<<2048, 256,  0, stream>>>(xyz, s_xyz, s_idx, bend, out_idx, out_pts);
}

// Round 14
// 223.255 us; speedup vs baseline: 1.2724x; 1.2724x over previous
//
#include <hip/hip_runtime.h>
#include <stdint.h>

// Problem constants: B=4, N=32768, K=16, nqueries=2048, stride=16.
#define NPTS  32768
#define NQ    2048
#define KNN   16
#define NB    4
#define NBUCK 512
#define Z0    (-5.2f)
#define ZSCALE (NBUCK / 10.4f)
#define INVS  (10.4f / NBUCK)

// ---- d_ws layout (1,851,392 B total; R12/R13 proved ws >= this) ----
// xs    : float [NB*NPTS]   @ 0          (524,288 B)  z-bucket-sorted coords (SoA)
// ys    : float [NB*NPTS]   @ 524,288
// zs    : float [NB*NPTS]   @ 1,048,576
// si    : ushort[NB*NPTS]   @ 1,572,864  (262,144 B)  original index per slot
// bend  : int   [NB*NBUCK]  @ 1,835,008  (  8,192 B)  inclusive bucket ends
// cursor: int   [NB*NBUCK]  @ 1,843,200  (  8,192 B)  scatter cursors (bucket starts)

__device__ __forceinline__ int zbucket(float z) {
    int bk = (int)((z - Z0) * ZSCALE);
    return min(max(bk, 0), NBUCK - 1);
}
__device__ __forceinline__ int dpp_shr1_i(int x) {
    return __builtin_amdgcn_update_dpp(x, x, 0x111, 0xf, 0xf, false);
}
__device__ __forceinline__ float dpp_shr1_f(float x) {
    return __int_as_float(dpp_shr1_i(__float_as_int(x)));
}
__device__ __forceinline__ float readlane_f(float x, int l) {
    return __int_as_float(__builtin_amdgcn_readlane(__float_as_int(x), l));
}

// Exact distributed top-16 (one query per wave): sorted list (ascending by
// (dist,idx)) in lanes 0..15; lane 15 holds exact threshold tau. d is the
// EXACT numpy distance. tg = tau*(1+1e-5): conservative fast-gate threshold.
__device__ __forceinline__ void insert1(float d, int p, bool act, int lane,
                                        float& ld, int& li, float& tau, float& tg)
{
    unsigned long long rem = __ballot(act && (d <= tau));
    while (rem) {
        const int srcl = __ffsll(rem) - 1;           // wave-uniform
        const float wd = readlane_f(d, srcl);
        const int   wi = __builtin_amdgcn_readlane(p, srcl);
        const bool less = (ld < wd) || (ld == wd && li < wi);
        const unsigned long long lm = __ballot(less);
        const int pos = __popc((unsigned)(lm & 0xffffull));
        const float pld = dpp_shr1_f(ld);
        const int   pli = dpp_shr1_i(li);
        if (lane < KNN) {
            if (lane == pos)      { ld = wd;  li = wi; }
            else if (lane > pos)  { ld = pld; li = pli; }
        }
        tau = readlane_f(ld, 15);
        rem &= rem - 1;
        if (rem) rem &= __ballot(d <= tau);          // re-gate survivors (exact)
    }
    tg = tau * 1.00001f;
}

// ---- prep 1: per-batch histogram + prefix scan (fused, 4 blocks x 1024) ----
__global__ __launch_bounds__(1024) void hist_scan_k(const float* __restrict__ xyz,
                                                    int* __restrict__ bend,
                                                    int* __restrict__ cursor)
{
    __shared__ int h[NBUCK];
    const int b = blockIdx.x, t = threadIdx.x;
    if (t < NBUCK) h[t] = 0;
    __syncthreads();
    const float* zp = xyz + (size_t)b * NPTS * 3 + 2;
    #pragma unroll
    for (int k = 0; k < NPTS / 1024; ++k)
        atomicAdd(&h[zbucket(zp[3 * (t + k * 1024)])], 1);
    __syncthreads();
    const int my = (t < NBUCK) ? h[t] : 0;
    for (int off = 1; off < NBUCK; off <<= 1) {      // Hillis-Steele inclusive
        const int v = (t < NBUCK && t >= off) ? h[t - off] : 0;
        __syncthreads();
        if (t < NBUCK) h[t] += v;
        __syncthreads();
    }
    if (t < NBUCK) {
        bend[b * NBUCK + t]   = h[t];                // inclusive end
        cursor[b * NBUCK + t] = h[t] - my;           // start (scatter cursor)
    }
}

// ---- prep 2: scatter into z-bucket order, SoA + packed ushort index ----
__global__ __launch_bounds__(256) void scatter_k(const float* __restrict__ xyz,
                                                 int* __restrict__ cursor,
                                                 float* __restrict__ xs,
                                                 float* __restrict__ ys,
                                                 float* __restrict__ zs,
                                                 unsigned short* __restrict__ si)
{
    const int i = blockIdx.x * 256 + threadIdx.x;    // [0, NB*NPTS)
    const int b = i >> 15, pi = i & (NPTS - 1);
    const float x = xyz[3 * (size_t)i + 0];
    const float y = xyz[3 * (size_t)i + 1];
    const float z = xyz[3 * (size_t)i + 2];
    const int pos = atomicAdd(&cursor[b * NBUCK + zbucket(z)], 1);
    const int o = b * NPTS + pos;
    xs[o] = x;  ys[o] = y;  zs[o] = z;
    si[o] = (unsigned short)pi;
}

// ---- query kernel: seed -> exact z-range -> dense ILP scan ----
__global__ __launch_bounds__(256) void knn_kernel(const float* __restrict__ xyz,
                                                  const float* __restrict__ xs,
                                                  const float* __restrict__ ys,
                                                  const float* __restrict__ zs,
                                                  const unsigned short* __restrict__ si,
                                                  const int* __restrict__ bend,
                                                  float* __restrict__ out_idx,
                                                  float* __restrict__ out_pts)
{
    const int tid  = threadIdx.x;
    const int lane = tid & 63;
    const int wv   = tid >> 6;
    const int w    = blockIdx.x * 4 + wv;            // wave = query, [0, 8192)
    const int b    = w >> 11;
    const int qi   = w & (NQ - 1);

    const float qx = xyz[(size_t)b * NPTS * 3 + 48 * qi + 0];
    const float qy = xyz[(size_t)b * NPTS * 3 + 48 * qi + 1];
    const float qz = xyz[(size_t)b * NPTS * 3 + 48 * qi + 2];

    const int g = b * NQ + qi;
    if (lane == 0) {
        out_pts[3 * g + 0] = qx;
        out_pts[3 * g + 1] = qy;
        out_pts[3 * g + 2] = qz;
    }

    const int cb = b * NBUCK;
    const float* bxs = xs + b * NPTS;
    const float* bys = ys + b * NPTS;
    const float* bzs = zs + b * NPTS;
    const unsigned short* bsi = si + b * NPTS;

    float ld = __builtin_inff();  int li = 0x7fffffff;
    float tau = __builtin_inff(), tg = __builtin_inff();

    // ---- seed: expand buckets around qb until >= 96 points, exact scan ----
    const int qb = zbucket(qz);
    int wd = 2;
    int lo_b = max(qb - wd, 0), hi_b = min(qb + wd, NBUCK - 1);
    int slo = (lo_b == 0) ? 0 : bend[cb + lo_b - 1];
    int shi = bend[cb + hi_b];
    while (shi - slo < 96 && (lo_b > 0 || hi_b < NBUCK - 1)) {
        wd <<= 1;
        lo_b = max(qb - wd, 0);  hi_b = min(qb + wd, NBUCK - 1);
        slo = (lo_b == 0) ? 0 : bend[cb + lo_b - 1];
        shi = bend[cb + hi_b];
    }
    for (int i = slo; i < shi; i += 64) {
        const int id = i + lane;
        const bool ok = id < shi;
        const int cid = ok ? id : slo;
        const float px = bxs[cid], py = bys[cid], pz = bzs[cid];
        const int  pidx = (int)bsi[cid];
        const float dx = __fadd_rn(px, -qx);         // exact numpy distance
        const float dy = __fadd_rn(py, -qy);
        const float dz = __fadd_rn(pz, -qz);
        const float d  = __fadd_rn(
            __fadd_rn(__fmul_rn(dx, dx), __fmul_rn(dy, dy)), __fmul_rn(dz, dz));
        insert1(d, pidx, ok, lane, ld, li, tau, tg);
    }
    // tau is now finite (seed >= 96 >= 16 points).

    // ---- exact prune range: |pz - qz| > r  =>  d > tau_seed >= tau_true ----
    const float r   = __fmul_rn(__builtin_sqrtf(tau), 1.000001f);
    const float flo = (qz - r - Z0) * ZSCALE - 0.01f;    // conservative margins
    const float fhi = (qz + r - Z0) * ZSCALE + 0.01f;    // (inf-safe via clamps)
    const int blo = (int)fmaxf(fminf(flo, (float)(NBUCK - 1)), 0.f);
    const int bhi = (int)fmaxf(fminf(fhi, (float)(NBUCK - 1)), 0.f);
    const int mlo = (blo == 0) ? 0 : bend[cb + blo - 1];
    const int mhi = bend[cb + bhi];

    // ---- dense ILP scan of [mlo,slo) and [shi,mhi) (seed excluded) ----
    #pragma unroll 1
    for (int half = 0; half < 2; ++half) {
        const int lo = half ? shi : mlo;
        const int hi = half ? mhi : slo;
        for (int i = lo; i < hi; i += 256) {
            float fx[4], fy[4], fz[4];
            int pid[4];  bool okv[4];
            #pragma unroll
            for (int j = 0; j < 4; ++j) {            // 16 coalesced loads in flight
                const int id = i + 64 * j + lane;
                okv[j] = id < hi;
                const int cid = okv[j] ? id : lo;
                fx[j] = bxs[cid];  fy[j] = bys[cid];  fz[j] = bzs[cid];
                pid[j] = (int)bsi[cid];
            }
            unsigned long long mm[4], any = 0;
            #pragma unroll
            for (int j = 0; j < 4; ++j) {            // fast FMA gate (superset)
                const float ax = fx[j] - qx, ay = fy[j] - qy, az = fz[j] - qz;
                const float gg = __fmaf_rn(az, az,
                                  __fmaf_rn(ay, ay, __fmul_rn(ax, ax)));
                mm[j] = __ballot(okv[j] && (gg <= tg));
                any |= mm[j];
            }
            if (any) {
                #pragma unroll
                for (int j = 0; j < 4; ++j) if (mm[j]) {
                    const float dx = __fadd_rn(fx[j], -qx);   // exact recompute
                    const float dy = __fadd_rn(fy[j], -qy);
                    const float dz = __fadd_rn(fz[j], -qz);
                    const float d  = __fadd_rn(
                        __fadd_rn(__fmul_rn(dx, dx), __fmul_rn(dy, dy)),
                        __fmul_rn(dz, dz));
                    insert1(d, pid[j], okv[j], lane, ld, li, tau, tg);
                }
            }
        }
    }

    if (lane < KNN)
        out_idx[(size_t)g * KNN + lane] = (float)li;
}

extern "C" void kernel_launch(void* const* d_in, const int* in_sizes, int n_in,
                              void* d_out, int out_size, void* d_ws, size_t ws_size,
                              hipStream_t stream) {
    const float* xyz = (const float*)d_in[0];
    float* out = (float*)d_out;
    float* out_idx = out;                                 // NB*NQ*KNN floats
    float* out_pts = out + (size_t)NB * NQ * KNN;         // NB*NQ*3 floats

    char* ws = (char*)d_ws;
    float* xs             = (float*)ws;
    float* ys             = (float*)(ws + 524288);
    float* zs             = (float*)(ws + 1048576);
    unsigned short* si    = (unsigned short*)(ws + 1572864);
    int* bend             = (int*)(ws + 1835008);
    int* cursor           = (int*)(ws + 1843200);

    hist_scan_k<<<NB,   1024, 0, stream>>>(xyz, bend, cursor);
    scatter_k  <<<512,  256,  0, stream>>>(xyz, cursor, xs, ys, zs, si);
    knn_kernel <<<2048, 256,  0, stream>>>(xyz, xs, ys, zs, si, bend,
                                           out_idx, out_pts);
}